// Round 9
// baseline (571.752 us; speedup 1.0000x reference)
//
#include <hip/hip_runtime.h>
#include <stdint.h>
#include <math.h>

#define NTOK   2048
#define DDIM   1024
#define ENUM   8
#define IDIM   2048
#define TWOI   4096
#define TOPKN  4
#define CAPROWS 10240   // 256-padding per expert: 8192 + 8*255 = 10232 -> 10240

typedef unsigned short ushort_t;
typedef __attribute__((ext_vector_type(8))) short short8;
typedef __attribute__((ext_vector_type(4))) float f4;

#define VMCNT(n) asm volatile("s_waitcnt vmcnt(" #n ")" ::: "memory")
#define CFENCE() asm volatile("" ::: "memory")
#define BARRIER() do { CFENCE(); __builtin_amdgcn_s_barrier(); CFENCE(); } while (0)

__device__ inline ushort_t f2bf(float f) {
    union { float f; uint32_t u; } v; v.f = f;
    uint32_t u = v.u;
    u += 0x7FFFu + ((u >> 16) & 1u);   // RNE
    return (ushort_t)(u >> 16);
}

// async global->LDS 16B/lane (gfx950). LDS dest = wave-uniform base + lane*16.
__device__ inline void gload16(const ushort_t* g, ushort_t* l) {
    __builtin_amdgcn_global_load_lds(
        (const __attribute__((address_space(1))) uint32_t*)(uintptr_t)g,
        (__attribute__((address_space(3))) uint32_t*)(uint32_t)(uintptr_t)l,
        16, 0, 0);
}

// ---------------- fp32 -> bf16 for both weight tensors + meta zeroing ----
__global__ void cvt_all_kernel(const float* __restrict__ gup, const float* __restrict__ dwn,
                               ushort_t* __restrict__ dst, int* __restrict__ meta) {
    if (blockIdx.x == 0 && threadIdx.x < 64) meta[threadIdx.x] = 0;
    const int n1 = ENUM * TWOI * DDIM / 8;   // float8 units
    const int n2 = ENUM * DDIM * IDIM / 8;
    int i = blockIdx.x * 256 + threadIdx.x;
    const float4* src;
    if (i < n1) src = (const float4*)gup + 2 * (size_t)i;
    else if (i < n1 + n2) src = (const float4*)dwn + 2 * (size_t)(i - n1);
    else return;
    float4 a = src[0], b = src[1];
    uint4 o;
    o.x = (uint32_t)f2bf(a.x) | ((uint32_t)f2bf(a.y) << 16);
    o.y = (uint32_t)f2bf(a.z) | ((uint32_t)f2bf(a.w) << 16);
    o.z = (uint32_t)f2bf(b.x) | ((uint32_t)f2bf(b.y) << 16);
    o.w = (uint32_t)f2bf(b.z) | ((uint32_t)f2bf(b.w) << 16);
    ((uint4*)dst)[i] = o;
}

// ---------------- router: float4 loads, fully unrolled, fp64 accum + fp64 top-k ----
__global__ void router_kernel(const float* __restrict__ x, const float* __restrict__ rw,
                              const float* __restrict__ rb, int* __restrict__ topk_idx,
                              float* __restrict__ topk_w, int* __restrict__ counts) {
    int n = (blockIdx.x * 256 + threadIdx.x) >> 6;   // one wave per token
    int lane = threadIdx.x & 63;
    const float4* x4 = (const float4*)(x + (size_t)n * DDIM);
    const float4* w4 = (const float4*)rw;
    double p[ENUM];
#pragma unroll
    for (int e = 0; e < ENUM; ++e) p[e] = 0.0;
#pragma unroll
    for (int c = 0; c < 4; ++c) {                    // 4 chunks x (64 lanes x 4 floats)
        float4 xv = x4[c * 64 + lane];
#pragma unroll
        for (int e = 0; e < ENUM; ++e) {
            float4 wv = w4[e * (DDIM / 4) + c * 64 + lane];
            p[e] += (double)xv.x * (double)wv.x;
            p[e] += (double)xv.y * (double)wv.y;
            p[e] += (double)xv.z * (double)wv.z;
            p[e] += (double)xv.w * (double)wv.w;
        }
    }
#pragma unroll
    for (int e = 0; e < ENUM; ++e) {
        double v = p[e];
#pragma unroll
        for (int off = 32; off > 0; off >>= 1) v += __shfl_xor(v, off, 64);
        p[e] = v + (double)rb[e];
    }
    if (lane == 0) {
        int id[TOPKN]; double lv[TOPKN]; unsigned used = 0;
#pragma unroll
        for (int k = 0; k < TOPKN; ++k) {
            double best = -INFINITY; int bi = 0;
            for (int e = 0; e < ENUM; ++e)
                if (!((used >> e) & 1u) && p[e] > best) { best = p[e]; bi = e; }
            used |= 1u << bi; id[k] = bi; lv[k] = best;
        }
        float lf[TOPKN]; float s = 0.f; float w[TOPKN];
#pragma unroll
        for (int k = 0; k < TOPKN; ++k) lf[k] = (float)lv[k];
#pragma unroll
        for (int k = 0; k < TOPKN; ++k) { w[k] = expf(lf[k] - lf[0]); s += w[k]; }
        float inv = 1.f / s;
#pragma unroll
        for (int k = 0; k < TOPKN; ++k) {
            topk_idx[n * TOPKN + k] = id[k];
            topk_w[n * TOPKN + k] = w[k] * inv;
            atomicAdd(&counts[id[k]], 1);
        }
    }
}

// ---------------- assign routed rows (256-aligned padding per expert) ----
__global__ void assign_kernel(const int* __restrict__ topk_idx, const float* __restrict__ topk_w,
                              const int* __restrict__ counts, int* __restrict__ fill,
                              int* __restrict__ row_token, float* __restrict__ row_weight,
                              int* __restrict__ row_of_pair,
                              int* __restrict__ base, int* __restrict__ padcnt,
                              int* __restrict__ totalp) {
    int baseL[ENUM]; int run = 0;
#pragma unroll
    for (int e = 0; e < ENUM; ++e) {
        baseL[e] = run;
        run += (counts[e] + 255) & ~255;
    }
    int n = blockIdx.x * 256 + threadIdx.x;
    if (n == 0) {
#pragma unroll
        for (int e = 0; e < ENUM; ++e) {
            base[e] = baseL[e];
            padcnt[e] = (counts[e] + 255) & ~255;
        }
        *totalp = run;
    }
    if (n >= NTOK) return;
    for (int k = 0; k < TOPKN; ++k) {
        int e = topk_idx[n * TOPKN + k];
        int pos = atomicAdd(&fill[e], 1);
        int row = baseL[e] + pos;
        row_token[row] = n;
        row_weight[row] = topk_w[n * TOPKN + k];
        row_of_pair[n * TOPKN + k] = row;
    }
}

// ---------------- gather tokens -> bf16 A matrix (zero pad rows) ----------------
__global__ void gather_kernel(const float* __restrict__ x, const int* __restrict__ row_token,
                              const int* __restrict__ base, const int* __restrict__ counts,
                              const int* __restrict__ padcnt, const int* __restrict__ totalp,
                              ushort_t* __restrict__ A) {
    int r = blockIdx.x;
    if (r >= *totalp) return;
    int e = 0;
#pragma unroll
    for (int i = 0; i < ENUM; ++i) if (r >= base[i] + padcnt[i]) e = i + 1;
    bool valid = (r - base[e]) < counts[e];
    int t = threadIdx.x;
    float4 v = make_float4(0.f, 0.f, 0.f, 0.f);
    if (valid) {
        int n = row_token[r];
        v = ((const float4*)(x + (size_t)n * DDIM))[t];
    }
    ushort4 o; o.x = f2bf(v.x); o.y = f2bf(v.y); o.z = f2bf(v.z); o.w = f2bf(v.w);
    ((ushort4*)(A + (size_t)r * DDIM))[t] = o;
}

// ============ GEMM1: 256-row x (128 gate + 128 up) tile, BK=64, 8 waves ============
// R4 config (best measured: ~105 us). DIAGNOSIS SPLIT: launched as TWO dispatches
// over mt ranges [0,4) and [4,8) (mt0 param) so each half is ~40-75 us and the
// rocprof top-5 list reveals the never-measured kernels (gemm2/cvt/...). The
// mt-split preserves block packing (d1 is nearly all-active, d2 is the tail).
__global__ __launch_bounds__(512, 2)
void gemm1_kernel(const ushort_t* __restrict__ A, const ushort_t* __restrict__ Wg,
                  const float* __restrict__ gub, ushort_t* __restrict__ act,
                  const int* __restrict__ base, const int* __restrict__ padcnt,
                  int mt0) {
    const int e = blockIdx.z;
    const int mt = mt0 + blockIdx.y;
    if (mt * 256 >= padcnt[e]) return;
    const int nt = blockIdx.x;               // 0..15 -> 128-wide slice of I dim
    const int row0 = base[e] + mt * 256;

    extern __shared__ char smem[];
    ushort_t* sA = (ushort_t*)smem;                    // 2 x 16384 elems
    ushort_t* sG = (ushort_t*)(smem + 65536);          // 2 x 8192 elems
    ushort_t* sU = (ushort_t*)(smem + 98304);          // 2 x 8192 elems

    const int t = threadIdx.x;
    const int lane = t & 63;
    const int wid = t >> 6;
    const int wm = wid >> 2;       // 0..1: row half (128 rows each)
    const int wn = wid & 3;        // 0..3: 32 gate cols + matching 32 up cols
    const int r15 = lane & 15, quad = lane >> 4;
    const int sw = r15 & 7;

    // staging source (swizzled column unit; (row+64j)&7 == row&7 so one swizzle)
    const int srow = t >> 3;                      // 0..63
    const int sunit = (t & 7) ^ (srow & 7);
    const ushort_t* gA = A + (size_t)(row0 + srow) * DDIM + sunit * 8;
    const ushort_t* gG = Wg + ((size_t)e * TWOI + nt * 128 + srow) * DDIM + sunit * 8;
    const ushort_t* gU = gG + (size_t)IDIM * DDIM;

    f4 accg[8][2], accu[8][2];
    const f4 zero = {0.f, 0.f, 0.f, 0.f};
#pragma unroll
    for (int i = 0; i < 8; ++i)
#pragma unroll
        for (int j = 0; j < 2; ++j) { accg[i][j] = zero; accu[i][j] = zero; }

#define STG1A1(ks, b) do {                                                   \
    const int k0_ = (ks) * 64;                                               \
    ushort_t* dA = sA + (b) * 16384 + t * 8;                                 \
    gload16(gA + k0_,                        dA);                            \
    gload16(gA + (size_t)64  * DDIM + k0_,   dA + 4096);                     \
} while (0)
#define STG1A2(ks, b) do {                                                   \
    const int k0_ = (ks) * 64;                                               \
    ushort_t* dA = sA + (b) * 16384 + t * 8;                                 \
    gload16(gA + (size_t)128 * DDIM + k0_,   dA + 8192);                     \
    gload16(gA + (size_t)192 * DDIM + k0_,   dA + 12288);                    \
} while (0)
#define STG1G(ks, b) do {                                                    \
    const int k0_ = (ks) * 64;                                               \
    ushort_t* dG = sG + (b) * 8192  + t * 8;                                 \
    gload16(gG + k0_,                        dG);                            \
    gload16(gG + (size_t)64 * DDIM + k0_,    dG + 4096);                     \
} while (0)
#define STG1U(ks, b) do {                                                    \
    const int k0_ = (ks) * 64;                                               \
    ushort_t* dU = sU + (b) * 8192  + t * 8;                                 \
    gload16(gU + k0_,                        dU);                            \
    gload16(gU + (size_t)64 * DDIM + k0_,    dU + 4096);                     \
} while (0)

    STG1A1(0, 0); STG1A2(0, 0); STG1G(0, 0); STG1U(0, 0);
    const int NKS = DDIM / 64;   // 16
    for (int ks = 0; ks < NKS; ++ks) {
        const int cur = ks & 1;
        VMCNT(0);                 // loads for cur issued a full K-step ago
        BARRIER();
        const ushort_t* bA = sA + cur * 16384;
        const ushort_t* bG = sG + cur * 8192;
        const ushort_t* bU = sU + cur * 8192;
        const bool pf = (ks + 1 < NKS);
#pragma unroll
        for (int kc = 0; kc < 2; ++kc) {
            const int uoff = ((kc * 4 + quad) ^ sw) * 8;    // elems
            short8 gF[2], uF[2];
#pragma unroll
            for (int j = 0; j < 2; ++j) {
                gF[j] = *(const short8*)(bG + (wn * 32 + j * 16 + r15) * 64 + uoff);
                uF[j] = *(const short8*)(bU + (wn * 32 + j * 16 + r15) * 64 + uoff);
            }
#pragma unroll
            for (int mh = 0; mh < 2; ++mh) {
                short8 aF[4];
#pragma unroll
                for (int i = 0; i < 4; ++i)
                    aF[i] = *(const short8*)(bA + (wm * 128 + (mh * 4 + i) * 16 + r15) * 64 + uoff);
                if (pf) {
                    if (kc == 0) { if (mh == 0) STG1A1(ks + 1, cur ^ 1); else STG1A2(ks + 1, cur ^ 1); }
                    else         { if (mh == 0) STG1G(ks + 1, cur ^ 1);  else STG1U(ks + 1, cur ^ 1); }
                }
                __builtin_amdgcn_sched_barrier(0);
                __builtin_amdgcn_s_setprio(1);
#pragma unroll
                for (int i = 0; i < 4; ++i)
#pragma unroll
                    for (int j = 0; j < 2; ++j) {
                        accg[mh * 4 + i][j] = __builtin_amdgcn_mfma_f32_16x16x32_bf16(aF[i], gF[j], accg[mh * 4 + i][j], 0, 0, 0);
                        accu[mh * 4 + i][j] = __builtin_amdgcn_mfma_f32_16x16x32_bf16(aF[i], uF[j], accu[mh * 4 + i][j], 0, 0, 0);
                    }
                __builtin_amdgcn_s_setprio(0);
                __builtin_amdgcn_sched_barrier(0);
            }
        }
    }
#undef STG1A1
#undef STG1A2
#undef STG1G
#undef STG1U

    const int rowbase = row0 + wm * 128;
    const int col0 = nt * 128 + wn * 32;
#pragma unroll
    for (int j = 0; j < 2; ++j) {
        const int col = col0 + j * 16 + r15;
        const float bg = gub[e * TWOI + col];
        const float bu = gub[e * TWOI + IDIM + col];
#pragma unroll
        for (int mf = 0; mf < 8; ++mf) {
#pragma unroll
            for (int r = 0; r < 4; ++r) {
                const int row = rowbase + mf * 16 + quad * 4 + r;
                float g = fminf(accg[mf][j][r] + bg, 7.0f);
                float u = fminf(fmaxf(accu[mf][j][r] + bu, -7.0f), 7.0f);
                float a = (u + 1.0f) * g / (1.0f + __expf(-1.702f * g));
                act[(size_t)row * IDIM + col] = f2bf(a);
            }
        }
    }
}

// ============ GEMM2: 128x128 tile, K=IDIM, BK=64, 4 waves, 2 blocks/CU ============
// R2 config verbatim (frozen for this diagnosis round).
__global__ __launch_bounds__(256, 2)
void gemm2_kernel(const ushort_t* __restrict__ A, const ushort_t* __restrict__ Wd,
                  const float* __restrict__ dwb, const float* __restrict__ row_weight,
                  float* __restrict__ contrib,
                  const int* __restrict__ base, const int* __restrict__ padcnt) {
    const int e = blockIdx.z;
    const int mt = blockIdx.y;
    if (mt * 128 >= padcnt[e]) return;
    const int nt = blockIdx.x;               // 0..7 -> 128-wide slice of D dim
    const int row0 = base[e] + mt * 128;

    extern __shared__ char smem[];
    ushort_t* sA = (ushort_t*)smem;                    // 2 x 8192 elems
    ushort_t* sB = (ushort_t*)(smem + 32768);          // 2 x 8192 elems

    const int t = threadIdx.x;
    const int lane = t & 63;
    const int wid = t >> 6;
    const int wm = wid >> 1;       // 0..1: 64-row half
    const int wn = wid & 1;        // 0..1: 64-col half
    const int r15 = lane & 15, quad = lane >> 4;
    const int sw = r15 & 7;

    const int gr = t >> 3;                        // 0..31
    const int gu = (t & 7) ^ (gr & 7);
    const ushort_t* gA = A + (size_t)(row0 + gr) * IDIM + gu * 8;
    const ushort_t* gB = Wd + ((size_t)e * DDIM + nt * 128 + gr) * IDIM + gu * 8;

    f4 acc[4][4];
    const f4 zero = {0.f, 0.f, 0.f, 0.f};
#pragma unroll
    for (int i = 0; i < 4; ++i)
#pragma unroll
        for (int j = 0; j < 4; ++j) acc[i][j] = zero;

#define STG2A(ks, b) do {                                                    \
    const int k0_ = (ks) * 64;                                               \
    ushort_t* dA = sA + (b) * 8192 + t * 8;                                  \
    gload16(gA + k0_,                       dA);                             \
    gload16(gA + (size_t)32 * IDIM + k0_,   dA + 2048);                      \
    gload16(gA + (size_t)64 * IDIM + k0_,   dA + 4096);                      \
    gload16(gA + (size_t)96 * IDIM + k0_,   dA + 6144);                      \
} while (0)
#define STG2B(ks, b) do {                                                    \
    const int k0_ = (ks) * 64;                                               \
    ushort_t* dB = sB + (b) * 8192 + t * 8;                                  \
    gload16(gB + k0_,                       dB);                             \
    gload16(gB + (size_t)32 * IDIM + k0_,   dB + 2048);                      \
    gload16(gB + (size_t)64 * IDIM + k0_,   dB + 4096);                      \
    gload16(gB + (size_t)96 * IDIM + k0_,   dB + 6144);                      \
} while (0)

    STG2A(0, 0); STG2B(0, 0);
    const int NKS = IDIM / 64;   // 32
    for (int ks = 0; ks < NKS; ++ks) {
        const int cur = ks & 1;
        VMCNT(0);
        BARRIER();
        const ushort_t* bA = sA + cur * 8192;
        const ushort_t* bB = sB + cur * 8192;
        const bool pf = (ks + 1 < NKS);
#pragma unroll
        for (int kc = 0; kc < 2; ++kc) {
            const int uoff = ((kc * 4 + quad) ^ sw) * 8;
            short8 aF[4], bF[4];
#pragma unroll
            for (int j = 0; j < 4; ++j)
                bF[j] = *(const short8*)(bB + (wn * 64 + j * 16 + r15) * 64 + uoff);
#pragma unroll
            for (int i = 0; i < 4; ++i)
                aF[i] = *(const short8*)(bA + (wm * 64 + i * 16 + r15) * 64 + uoff);
            if (pf) {
                if (kc == 0) STG2A(ks + 1, cur ^ 1);
                else         STG2B(ks + 1, cur ^ 1);
            }
            __builtin_amdgcn_sched_barrier(0);
            __builtin_amdgcn_s_setprio(1);
#pragma unroll
            for (int i = 0; i < 4; ++i)
#pragma unroll
                for (int j = 0; j < 4; ++j)
                    acc[i][j] = __builtin_amdgcn_mfma_f32_16x16x32_bf16(aF[i], bF[j], acc[i][j], 0, 0, 0);
            __builtin_amdgcn_s_setprio(0);
            __builtin_amdgcn_sched_barrier(0);
        }
    }
#undef STG2A
#undef STG2B

    const int rowbase = row0 + wm * 64;
    const int col0 = nt * 128 + wn * 64;
    float bs[4];
#pragma unroll
    for (int j = 0; j < 4; ++j) bs[j] = dwb[e * DDIM + col0 + j * 16 + r15];
#pragma unroll
    for (int mf = 0; mf < 4; ++mf) {
#pragma unroll
        for (int r = 0; r < 4; ++r) {
            const int row = rowbase + mf * 16 + quad * 4 + r;
            const float w = row_weight[row];
#pragma unroll
            for (int j = 0; j < 4; ++j) {
                const int col = col0 + j * 16 + r15;
                contrib[(size_t)row * DDIM + col] = (acc[mf][j][r] + bs[j]) * w;
            }
        }
    }
}

// ---------------- combine 4 contributions per token ----------------
__global__ void combine_kernel(const float* __restrict__ contrib, const int* __restrict__ row_of_pair,
                               float* __restrict__ out) {
    int n = blockIdx.x;
    int t = threadIdx.x;
    int r0 = row_of_pair[n * 4 + 0], r1 = row_of_pair[n * 4 + 1];
    int r2 = row_of_pair[n * 4 + 2], r3 = row_of_pair[n * 4 + 3];
    float4 a = ((const float4*)(contrib + (size_t)r0 * DDIM))[t];
    float4 b = ((const float4*)(contrib + (size_t)r1 * DDIM))[t];
    float4 c = ((const float4*)(contrib + (size_t)r2 * DDIM))[t];
    float4 d = ((const float4*)(contrib + (size_t)r3 * DDIM))[t];
    float4 s;
    s.x = a.x + b.x + c.x + d.x;
    s.y = a.y + b.y + c.y + d.y;
    s.z = a.z + b.z + c.z + d.z;
    s.w = a.w + b.w + c.w + d.w;
    ((float4*)(out + (size_t)n * DDIM))[t] = s;
}

extern "C" void kernel_launch(void* const* d_in, const int* in_sizes, int n_in,
                              void* d_out, int out_size, void* d_ws, size_t ws_size,
                              hipStream_t stream) {
    const float* x   = (const float*)d_in[0];
    const float* rw  = (const float*)d_in[1];
    const float* rb  = (const float*)d_in[2];
    const float* gup = (const float*)d_in[3];
    const float* gub = (const float*)d_in[4];
    const float* dwn = (const float*)d_in[5];
    const float* dwb = (const float*)d_in[6];
    float* out = (float*)d_out;

    char* ws = (char*)d_ws;
    size_t off = 0;
    auto alloc = [&](size_t bytes) -> void* {
        void* p = ws + off;
        off += (bytes + 255) & ~(size_t)255;
        return p;
    };
    ushort_t* Wg   = (ushort_t*)alloc((size_t)ENUM * TWOI * DDIM * 2);  // 67.1 MB
    ushort_t* Wd   = (ushort_t*)alloc((size_t)ENUM * DDIM * IDIM * 2);  // 33.6 MB (contiguous after Wg)
    // Ar (bf16 gathered tokens, live gather->gemm1) overlaid with CONTRIB (fp32,
    // live gemm2->combine) -- disjoint lifetimes, union sized for CONTRIB.
    char* unionbuf = (char*)alloc((size_t)CAPROWS * DDIM * 4);          // 41.9 MB
    ushort_t* Ar      = (ushort_t*)unionbuf;
    float*    CONTRIB = (float*)unionbuf;
    ushort_t* ACT  = (ushort_t*)alloc((size_t)CAPROWS * IDIM * 2);      // 41.9 MB
    int*   topk_idx    = (int*)alloc(NTOK * 4 * 4);
    float* topk_w      = (float*)alloc(NTOK * 4 * 4);
    int*   row_of_pair = (int*)alloc(NTOK * 4 * 4);
    int*   row_token   = (int*)alloc(CAPROWS * 4);
    float* row_weight  = (float*)alloc(CAPROWS * 4);
    int*   meta        = (int*)alloc(256);
    int* counts = meta;      int* fill = meta + 8;
    int* base   = meta + 16; int* padcnt = meta + 24;
    int* totalp = meta + 32;

    const int ncvt8 = (ENUM * TWOI * DDIM + ENUM * DDIM * IDIM) / 8;

    cvt_all_kernel<<<(ncvt8 + 255) / 256, 256, 0, stream>>>(gup, dwn, Wg, meta);
    router_kernel<<<NTOK / 4, 256, 0, stream>>>(x, rw, rb, topk_idx, topk_w, counts);
    assign_kernel<<<NTOK / 256, 256, 0, stream>>>(topk_idx, topk_w, counts, fill,
                                                  row_token, row_weight, row_of_pair,
                                                  base, padcnt, totalp);
    gather_kernel<<<CAPROWS, 256, 0, stream>>>(x, row_token, base, counts, padcnt, totalp, Ar);
    // DIAGNOSIS SPLIT: two gemm1 dispatches (mt 0..3 and mt 4..7) so top-5
    // rocprof slots reveal gemm2/cvt/etc. Same total work & packing.
    gemm1_kernel<<<dim3(IDIM / 128, 4, ENUM), 512, 131072, stream>>>(Ar, Wg, gub, ACT, base, padcnt, 0);
    gemm1_kernel<<<dim3(IDIM / 128, 4, ENUM), 512, 131072, stream>>>(Ar, Wg, gub, ACT, base, padcnt, 4);
    gemm2_kernel<<<dim3(DDIM / 128, 16, ENUM), 256, 65536, stream>>>(ACT, Wd, dwb, row_weight, CONTRIB, base, padcnt);
    combine_kernel<<<NTOK, 256, 0, stream>>>(CONTRIB, row_of_pair, out);
}

// Round 10
// 455.855 us; speedup vs baseline: 1.2542x; 1.2542x over previous
//
#include <hip/hip_runtime.h>
#include <stdint.h>
#include <math.h>

#define NTOK   2048
#define DDIM   1024
#define ENUM   8
#define IDIM   2048
#define TWOI   4096
#define TOPKN  4
#define CAPROWS 10240   // 256-padding per expert: 8192 + 8*255 = 10232 -> 10240

typedef unsigned short ushort_t;
typedef __attribute__((ext_vector_type(8))) short short8;
typedef __attribute__((ext_vector_type(4))) float f4;

#define VMCNT(n) asm volatile("s_waitcnt vmcnt(" #n ")" ::: "memory")
#define CFENCE() asm volatile("" ::: "memory")
#define BARRIER() do { CFENCE(); __builtin_amdgcn_s_barrier(); CFENCE(); } while (0)

__device__ inline ushort_t f2bf(float f) {
    union { float f; uint32_t u; } v; v.f = f;
    uint32_t u = v.u;
    u += 0x7FFFu + ((u >> 16) & 1u);   // RNE
    return (ushort_t)(u >> 16);
}

// async global->LDS 16B/lane (gfx950). LDS dest = wave-uniform base + lane*16.
__device__ inline void gload16(const ushort_t* g, ushort_t* l) {
    __builtin_amdgcn_global_load_lds(
        (const __attribute__((address_space(1))) uint32_t*)(uintptr_t)g,
        (__attribute__((address_space(3))) uint32_t*)(uint32_t)(uintptr_t)l,
        16, 0, 0);
}

// ---------------- fp32 -> bf16 for both weight tensors + meta zeroing ----
__global__ void cvt_all_kernel(const float* __restrict__ gup, const float* __restrict__ dwn,
                               ushort_t* __restrict__ dst, int* __restrict__ meta) {
    if (blockIdx.x == 0 && threadIdx.x < 64) meta[threadIdx.x] = 0;
    const int n1 = ENUM * TWOI * DDIM / 8;   // float8 units
    const int n2 = ENUM * DDIM * IDIM / 8;
    int i = blockIdx.x * 256 + threadIdx.x;
    const float4* src;
    if (i < n1) src = (const float4*)gup + 2 * (size_t)i;
    else if (i < n1 + n2) src = (const float4*)dwn + 2 * (size_t)(i - n1);
    else return;
    float4 a = src[0], b = src[1];
    uint4 o;
    o.x = (uint32_t)f2bf(a.x) | ((uint32_t)f2bf(a.y) << 16);
    o.y = (uint32_t)f2bf(a.z) | ((uint32_t)f2bf(a.w) << 16);
    o.z = (uint32_t)f2bf(b.x) | ((uint32_t)f2bf(b.y) << 16);
    o.w = (uint32_t)f2bf(b.z) | ((uint32_t)f2bf(b.w) << 16);
    ((uint4*)dst)[i] = o;
}

// ---------------- router: float4 GEMV + fp64 top-k. NO ATOMICS (R9 showed the
// 8192 same-line atomicAdds were the entire 103 us; counting moved to schedule). ----
__global__ void router_kernel(const float* __restrict__ x, const float* __restrict__ rw,
                              const float* __restrict__ rb, int* __restrict__ topk_idx,
                              float* __restrict__ topk_w) {
    int n = (blockIdx.x * 256 + threadIdx.x) >> 6;   // one wave per token
    int lane = threadIdx.x & 63;
    const float4* x4 = (const float4*)(x + (size_t)n * DDIM);
    const float4* w4 = (const float4*)rw;
    double p[ENUM];
#pragma unroll
    for (int e = 0; e < ENUM; ++e) p[e] = 0.0;
#pragma unroll
    for (int c = 0; c < 4; ++c) {                    // 4 chunks x (64 lanes x 4 floats)
        float4 xv = x4[c * 64 + lane];
#pragma unroll
        for (int e = 0; e < ENUM; ++e) {
            float4 wv = w4[e * (DDIM / 4) + c * 64 + lane];
            p[e] += (double)xv.x * (double)wv.x;
            p[e] += (double)xv.y * (double)wv.y;
            p[e] += (double)xv.z * (double)wv.z;
            p[e] += (double)xv.w * (double)wv.w;
        }
    }
#pragma unroll
    for (int e = 0; e < ENUM; ++e) {
        double v = p[e];
#pragma unroll
        for (int off = 32; off > 0; off >>= 1) v += __shfl_xor(v, off, 64);
        p[e] = v + (double)rb[e];
    }
    if (lane == 0) {
        int id[TOPKN]; double lv[TOPKN]; unsigned used = 0;
#pragma unroll
        for (int k = 0; k < TOPKN; ++k) {
            double best = -INFINITY; int bi = 0;
            for (int e = 0; e < ENUM; ++e)
                if (!((used >> e) & 1u) && p[e] > best) { best = p[e]; bi = e; }
            used |= 1u << bi; id[k] = bi; lv[k] = best;
        }
        float lf[TOPKN]; float s = 0.f; float w[TOPKN];
#pragma unroll
        for (int k = 0; k < TOPKN; ++k) lf[k] = (float)lv[k];
#pragma unroll
        for (int k = 0; k < TOPKN; ++k) { w[k] = expf(lf[k] - lf[0]); s += w[k]; }
        float inv = 1.f / s;
#pragma unroll
        for (int k = 0; k < TOPKN; ++k) {
            topk_idx[n * TOPKN + k] = id[k];
            topk_w[n * TOPKN + k] = w[k] * inv;
        }
    }
}

// ---------------- schedule: atomic-free deterministic routing build ----------------
// One block x 1024 threads; each thread owns 8 consecutive pairs. Hierarchical
// stable rank: per-thread static counts -> wave shfl_up scan -> LDS wave totals ->
// thread-0 block scan (counts/base/padcnt/totalp) -> per-expert static assignment
// loops (no runtime-indexed register arrays anywhere -> no scratch).
__global__ void schedule_kernel(const int* __restrict__ topk_idx, const float* __restrict__ topk_w,
                                int* __restrict__ row_token, float* __restrict__ row_weight,
                                int* __restrict__ row_of_pair,
                                int* __restrict__ counts, int* __restrict__ base,
                                int* __restrict__ padcnt, int* __restrict__ totalp) {
    __shared__ int wtot[16][ENUM];
    __shared__ int wpre[16][ENUM];
    __shared__ int sbase[ENUM];
    const int t = threadIdx.x;           // 0..1023
    const int lane = t & 63, wv = t >> 6;

    int e8[8]; float w8[8];
#pragma unroll
    for (int j = 0; j < 8; ++j) {
        e8[j] = topk_idx[t * 8 + j];
        w8[j] = topk_w[t * 8 + j];
    }
    int lc[ENUM], inc[ENUM];
#pragma unroll
    for (int e = 0; e < ENUM; ++e) {
        int c = 0;
#pragma unroll
        for (int j = 0; j < 8; ++j) c += (e8[j] == e) ? 1 : 0;
        lc[e] = c;
        int v = c;
#pragma unroll
        for (int off = 1; off < 64; off <<= 1) {
            int u = __shfl_up(v, off, 64);
            if (lane >= off) v += u;
        }
        inc[e] = v;                       // wave-inclusive prefix
    }
    if (lane == 63) {
#pragma unroll
        for (int e = 0; e < ENUM; ++e) wtot[wv][e] = inc[e];
    }
    __syncthreads();
    if (t == 0) {
        int runb = 0;
        for (int e = 0; e < ENUM; ++e) {
            int run = 0;
            for (int w = 0; w < 16; ++w) { wpre[w][e] = run; run += wtot[w][e]; }
            counts[e] = run;
            base[e] = runb;
            sbase[e] = runb;
            int pc = (run + 255) & ~255;
            padcnt[e] = pc;
            runb += pc;
        }
        *totalp = runb;
    }
    __syncthreads();
#pragma unroll
    for (int e = 0; e < ENUM; ++e) {
        int pos = sbase[e] + wpre[wv][e] + (inc[e] - lc[e]);
#pragma unroll
        for (int j = 0; j < 8; ++j) {
            if (e8[j] == e) {
                row_token[pos] = (t * 8 + j) >> 2;
                row_weight[pos] = w8[j];
                row_of_pair[t * 8 + j] = pos;
                ++pos;
            }
        }
    }
}

// ---------------- gather tokens -> bf16 A matrix (zero pad rows) ----------------
__global__ void gather_kernel(const float* __restrict__ x, const int* __restrict__ row_token,
                              const int* __restrict__ base, const int* __restrict__ counts,
                              const int* __restrict__ padcnt, const int* __restrict__ totalp,
                              ushort_t* __restrict__ A) {
    int r = blockIdx.x;
    if (r >= *totalp) return;
    int e = 0;
#pragma unroll
    for (int i = 0; i < ENUM; ++i) if (r >= base[i] + padcnt[i]) e = i + 1;
    bool valid = (r - base[e]) < counts[e];
    int t = threadIdx.x;
    float4 v = make_float4(0.f, 0.f, 0.f, 0.f);
    if (valid) {
        int n = row_token[r];
        v = ((const float4*)(x + (size_t)n * DDIM))[t];
    }
    ushort4 o; o.x = f2bf(v.x); o.y = f2bf(v.y); o.z = f2bf(v.z); o.w = f2bf(v.w);
    ((ushort4*)(A + (size_t)r * DDIM))[t] = o;
}

// ============ GEMM1: 256-row x (128 gate + 128 up) tile, BK=64, 8 waves ============
// R4/R8 config (best measured ~105 us). launch_bounds(512,2): acc needs 128
// regs/thread -- (512,4) spills catastrophically (R7: 1 GB scratch traffic).
__global__ __launch_bounds__(512, 2)
void gemm1_kernel(const ushort_t* __restrict__ A, const ushort_t* __restrict__ Wg,
                  const float* __restrict__ gub, ushort_t* __restrict__ act,
                  const int* __restrict__ base, const int* __restrict__ padcnt) {
    const int e = blockIdx.z;
    const int mt = blockIdx.y;
    if (mt * 256 >= padcnt[e]) return;
    const int nt = blockIdx.x;               // 0..15 -> 128-wide slice of I dim
    const int row0 = base[e] + mt * 256;

    extern __shared__ char smem[];
    ushort_t* sA = (ushort_t*)smem;                    // 2 x 16384 elems
    ushort_t* sG = (ushort_t*)(smem + 65536);          // 2 x 8192 elems
    ushort_t* sU = (ushort_t*)(smem + 98304);          // 2 x 8192 elems

    const int t = threadIdx.x;
    const int lane = t & 63;
    const int wid = t >> 6;
    const int wm = wid >> 2;       // 0..1: row half (128 rows each)
    const int wn = wid & 3;        // 0..3: 32 gate cols + matching 32 up cols
    const int r15 = lane & 15, quad = lane >> 4;
    const int sw = r15 & 7;

    const int srow = t >> 3;                      // 0..63
    const int sunit = (t & 7) ^ (srow & 7);
    const ushort_t* gA = A + (size_t)(row0 + srow) * DDIM + sunit * 8;
    const ushort_t* gG = Wg + ((size_t)e * TWOI + nt * 128 + srow) * DDIM + sunit * 8;
    const ushort_t* gU = gG + (size_t)IDIM * DDIM;

    f4 accg[8][2], accu[8][2];
    const f4 zero = {0.f, 0.f, 0.f, 0.f};
#pragma unroll
    for (int i = 0; i < 8; ++i)
#pragma unroll
        for (int j = 0; j < 2; ++j) { accg[i][j] = zero; accu[i][j] = zero; }

#define STG1A1(ks, b) do {                                                   \
    const int k0_ = (ks) * 64;                                               \
    ushort_t* dA = sA + (b) * 16384 + t * 8;                                 \
    gload16(gA + k0_,                        dA);                            \
    gload16(gA + (size_t)64  * DDIM + k0_,   dA + 4096);                     \
} while (0)
#define STG1A2(ks, b) do {                                                   \
    const int k0_ = (ks) * 64;                                               \
    ushort_t* dA = sA + (b) * 16384 + t * 8;                                 \
    gload16(gA + (size_t)128 * DDIM + k0_,   dA + 8192);                     \
    gload16(gA + (size_t)192 * DDIM + k0_,   dA + 12288);                    \
} while (0)
#define STG1G(ks, b) do {                                                    \
    const int k0_ = (ks) * 64;                                               \
    ushort_t* dG = sG + (b) * 8192  + t * 8;                                 \
    gload16(gG + k0_,                        dG);                            \
    gload16(gG + (size_t)64 * DDIM + k0_,    dG + 4096);                     \
} while (0)
#define STG1U(ks, b) do {                                                    \
    const int k0_ = (ks) * 64;                                               \
    ushort_t* dU = sU + (b) * 8192  + t * 8;                                 \
    gload16(gU + k0_,                        dU);                            \
    gload16(gU + (size_t)64 * DDIM + k0_,    dU + 4096);                     \
} while (0)

    STG1A1(0, 0); STG1A2(0, 0); STG1G(0, 0); STG1U(0, 0);
    const int NKS = DDIM / 64;   // 16
    for (int ks = 0; ks < NKS; ++ks) {
        const int cur = ks & 1;
        VMCNT(0);                 // loads for cur issued a full K-step ago
        BARRIER();
        const ushort_t* bA = sA + cur * 16384;
        const ushort_t* bG = sG + cur * 8192;
        const ushort_t* bU = sU + cur * 8192;
        const bool pf = (ks + 1 < NKS);
#pragma unroll
        for (int kc = 0; kc < 2; ++kc) {
            const int uoff = ((kc * 4 + quad) ^ sw) * 8;    // elems
            short8 gF[2], uF[2];
#pragma unroll
            for (int j = 0; j < 2; ++j) {
                gF[j] = *(const short8*)(bG + (wn * 32 + j * 16 + r15) * 64 + uoff);
                uF[j] = *(const short8*)(bU + (wn * 32 + j * 16 + r15) * 64 + uoff);
            }
#pragma unroll
            for (int mh = 0; mh < 2; ++mh) {
                short8 aF[4];
#pragma unroll
                for (int i = 0; i < 4; ++i)
                    aF[i] = *(const short8*)(bA + (wm * 128 + (mh * 4 + i) * 16 + r15) * 64 + uoff);
                if (pf) {
                    if (kc == 0) { if (mh == 0) STG1A1(ks + 1, cur ^ 1); else STG1A2(ks + 1, cur ^ 1); }
                    else         { if (mh == 0) STG1G(ks + 1, cur ^ 1);  else STG1U(ks + 1, cur ^ 1); }
                }
                __builtin_amdgcn_sched_barrier(0);
                __builtin_amdgcn_s_setprio(1);
#pragma unroll
                for (int i = 0; i < 4; ++i)
#pragma unroll
                    for (int j = 0; j < 2; ++j) {
                        accg[mh * 4 + i][j] = __builtin_amdgcn_mfma_f32_16x16x32_bf16(aF[i], gF[j], accg[mh * 4 + i][j], 0, 0, 0);
                        accu[mh * 4 + i][j] = __builtin_amdgcn_mfma_f32_16x16x32_bf16(aF[i], uF[j], accu[mh * 4 + i][j], 0, 0, 0);
                    }
                __builtin_amdgcn_s_setprio(0);
                __builtin_amdgcn_sched_barrier(0);
            }
        }
    }
#undef STG1A1
#undef STG1A2
#undef STG1G
#undef STG1U

    const int rowbase = row0 + wm * 128;
    const int col0 = nt * 128 + wn * 32;
#pragma unroll
    for (int j = 0; j < 2; ++j) {
        const int col = col0 + j * 16 + r15;
        const float bg = gub[e * TWOI + col];
        const float bu = gub[e * TWOI + IDIM + col];
#pragma unroll
        for (int mf = 0; mf < 8; ++mf) {
#pragma unroll
            for (int r = 0; r < 4; ++r) {
                const int row = rowbase + mf * 16 + quad * 4 + r;
                float g = fminf(accg[mf][j][r] + bg, 7.0f);
                float u = fminf(fmaxf(accu[mf][j][r] + bu, -7.0f), 7.0f);
                float a = (u + 1.0f) * g / (1.0f + __expf(-1.702f * g));
                act[(size_t)row * IDIM + col] = f2bf(a);
            }
        }
    }
}

// ============ GEMM2: 128x128 tile, K=IDIM, BK=64, 4 waves, 2 blocks/CU ============
// R2 config verbatim.
__global__ __launch_bounds__(256, 2)
void gemm2_kernel(const ushort_t* __restrict__ A, const ushort_t* __restrict__ Wd,
                  const float* __restrict__ dwb, const float* __restrict__ row_weight,
                  float* __restrict__ contrib,
                  const int* __restrict__ base, const int* __restrict__ padcnt) {
    const int e = blockIdx.z;
    const int mt = blockIdx.y;
    if (mt * 128 >= padcnt[e]) return;
    const int nt = blockIdx.x;               // 0..7 -> 128-wide slice of D dim
    const int row0 = base[e] + mt * 128;

    extern __shared__ char smem[];
    ushort_t* sA = (ushort_t*)smem;                    // 2 x 8192 elems
    ushort_t* sB = (ushort_t*)(smem + 32768);          // 2 x 8192 elems

    const int t = threadIdx.x;
    const int lane = t & 63;
    const int wid = t >> 6;
    const int wm = wid >> 1;       // 0..1: 64-row half
    const int wn = wid & 1;        // 0..1: 64-col half
    const int r15 = lane & 15, quad = lane >> 4;
    const int sw = r15 & 7;

    const int gr = t >> 3;                        // 0..31
    const int gu = (t & 7) ^ (gr & 7);
    const ushort_t* gA = A + (size_t)(row0 + gr) * IDIM + gu * 8;
    const ushort_t* gB = Wd + ((size_t)e * DDIM + nt * 128 + gr) * IDIM + gu * 8;

    f4 acc[4][4];
    const f4 zero = {0.f, 0.f, 0.f, 0.f};
#pragma unroll
    for (int i = 0; i < 4; ++i)
#pragma unroll
        for (int j = 0; j < 4; ++j) acc[i][j] = zero;

#define STG2A(ks, b) do {                                                    \
    const int k0_ = (ks) * 64;                                               \
    ushort_t* dA = sA + (b) * 8192 + t * 8;                                  \
    gload16(gA + k0_,                       dA);                             \
    gload16(gA + (size_t)32 * IDIM + k0_,   dA + 2048);                      \
    gload16(gA + (size_t)64 * IDIM + k0_,   dA + 4096);                      \
    gload16(gA + (size_t)96 * IDIM + k0_,   dA + 6144);                      \
} while (0)
#define STG2B(ks, b) do {                                                    \
    const int k0_ = (ks) * 64;                                               \
    ushort_t* dB = sB + (b) * 8192 + t * 8;                                  \
    gload16(gB + k0_,                       dB);                             \
    gload16(gB + (size_t)32 * IDIM + k0_,   dB + 2048);                      \
    gload16(gB + (size_t)64 * IDIM + k0_,   dB + 4096);                      \
    gload16(gB + (size_t)96 * IDIM + k0_,   dB + 6144);                      \
} while (0)

    STG2A(0, 0); STG2B(0, 0);
    const int NKS = IDIM / 64;   // 32
    for (int ks = 0; ks < NKS; ++ks) {
        const int cur = ks & 1;
        VMCNT(0);
        BARRIER();
        const ushort_t* bA = sA + cur * 8192;
        const ushort_t* bB = sB + cur * 8192;
        const bool pf = (ks + 1 < NKS);
#pragma unroll
        for (int kc = 0; kc < 2; ++kc) {
            const int uoff = ((kc * 4 + quad) ^ sw) * 8;
            short8 aF[4], bF[4];
#pragma unroll
            for (int j = 0; j < 4; ++j)
                bF[j] = *(const short8*)(bB + (wn * 64 + j * 16 + r15) * 64 + uoff);
#pragma unroll
            for (int i = 0; i < 4; ++i)
                aF[i] = *(const short8*)(bA + (wm * 64 + i * 16 + r15) * 64 + uoff);
            if (pf) {
                if (kc == 0) STG2A(ks + 1, cur ^ 1);
                else         STG2B(ks + 1, cur ^ 1);
            }
            __builtin_amdgcn_sched_barrier(0);
            __builtin_amdgcn_s_setprio(1);
#pragma unroll
            for (int i = 0; i < 4; ++i)
#pragma unroll
                for (int j = 0; j < 4; ++j)
                    acc[i][j] = __builtin_amdgcn_mfma_f32_16x16x32_bf16(aF[i], bF[j], acc[i][j], 0, 0, 0);
            __builtin_amdgcn_s_setprio(0);
            __builtin_amdgcn_sched_barrier(0);
        }
    }
#undef STG2A
#undef STG2B

    const int rowbase = row0 + wm * 64;
    const int col0 = nt * 128 + wn * 64;
    float bs[4];
#pragma unroll
    for (int j = 0; j < 4; ++j) bs[j] = dwb[e * DDIM + col0 + j * 16 + r15];
#pragma unroll
    for (int mf = 0; mf < 4; ++mf) {
#pragma unroll
        for (int r = 0; r < 4; ++r) {
            const int row = rowbase + mf * 16 + quad * 4 + r;
            const float w = row_weight[row];
#pragma unroll
            for (int j = 0; j < 4; ++j) {
                const int col = col0 + j * 16 + r15;
                contrib[(size_t)row * DDIM + col] = (acc[mf][j][r] + bs[j]) * w;
            }
        }
    }
}

// ---------------- combine 4 contributions per token ----------------
__global__ void combine_kernel(const float* __restrict__ contrib, const int* __restrict__ row_of_pair,
                               float* __restrict__ out) {
    int n = blockIdx.x;
    int t = threadIdx.x;
    int r0 = row_of_pair[n * 4 + 0], r1 = row_of_pair[n * 4 + 1];
    int r2 = row_of_pair[n * 4 + 2], r3 = row_of_pair[n * 4 + 3];
    float4 a = ((const float4*)(contrib + (size_t)r0 * DDIM))[t];
    float4 b = ((const float4*)(contrib + (size_t)r1 * DDIM))[t];
    float4 c = ((const float4*)(contrib + (size_t)r2 * DDIM))[t];
    float4 d = ((const float4*)(contrib + (size_t)r3 * DDIM))[t];
    float4 s;
    s.x = a.x + b.x + c.x + d.x;
    s.y = a.y + b.y + c.y + d.y;
    s.z = a.z + b.z + c.z + d.z;
    s.w = a.w + b.w + c.w + d.w;
    ((float4*)(out + (size_t)n * DDIM))[t] = s;
}

extern "C" void kernel_launch(void* const* d_in, const int* in_sizes, int n_in,
                              void* d_out, int out_size, void* d_ws, size_t ws_size,
                              hipStream_t stream) {
    const float* x   = (const float*)d_in[0];
    const float* rw  = (const float*)d_in[1];
    const float* rb  = (const float*)d_in[2];
    const float* gup = (const float*)d_in[3];
    const float* gub = (const float*)d_in[4];
    const float* dwn = (const float*)d_in[5];
    const float* dwb = (const float*)d_in[6];
    float* out = (float*)d_out;

    char* ws = (char*)d_ws;
    size_t off = 0;
    auto alloc = [&](size_t bytes) -> void* {
        void* p = ws + off;
        off += (bytes + 255) & ~(size_t)255;
        return p;
    };
    ushort_t* Wg   = (ushort_t*)alloc((size_t)ENUM * TWOI * DDIM * 2);  // 67.1 MB
    ushort_t* Wd   = (ushort_t*)alloc((size_t)ENUM * DDIM * IDIM * 2);  // 33.6 MB (contiguous after Wg)
    // Ar (bf16 gathered tokens, live gather->gemm1) overlaid with CONTRIB (fp32,
    // live gemm2->combine) -- disjoint lifetimes, union sized for CONTRIB.
    char* unionbuf = (char*)alloc((size_t)CAPROWS * DDIM * 4);          // 41.9 MB
    ushort_t* Ar      = (ushort_t*)unionbuf;
    float*    CONTRIB = (float*)unionbuf;
    ushort_t* ACT  = (ushort_t*)alloc((size_t)CAPROWS * IDIM * 2);      // 41.9 MB
    int*   topk_idx    = (int*)alloc(NTOK * 4 * 4);
    float* topk_w      = (float*)alloc(NTOK * 4 * 4);
    int*   row_of_pair = (int*)alloc(NTOK * 4 * 4);
    int*   row_token   = (int*)alloc(CAPROWS * 4);
    float* row_weight  = (float*)alloc(CAPROWS * 4);
    int*   meta        = (int*)alloc(256);
    int* counts = meta;      // meta+8 (old fill) unused now
    int* base   = meta + 16; int* padcnt = meta + 24;
    int* totalp = meta + 32;

    const int ncvt8 = (ENUM * TWOI * DDIM + ENUM * DDIM * IDIM) / 8;

    cvt_all_kernel<<<(ncvt8 + 255) / 256, 256, 0, stream>>>(gup, dwn, Wg, meta);
    router_kernel<<<NTOK / 4, 256, 0, stream>>>(x, rw, rb, topk_idx, topk_w);
    schedule_kernel<<<1, 1024, 0, stream>>>(topk_idx, topk_w, row_token, row_weight,
                                            row_of_pair, counts, base, padcnt, totalp);
    gather_kernel<<<CAPROWS, 256, 0, stream>>>(x, row_token, base, counts, padcnt, totalp, Ar);
    gemm1_kernel<<<dim3(IDIM / 128, 8, ENUM), 512, 131072, stream>>>(Ar, Wg, gub, ACT, base, padcnt);
    gemm2_kernel<<<dim3(DDIM / 128, 16, ENUM), 256, 65536, stream>>>(ACT, Wd, dwb, row_weight, CONTRIB, base, padcnt);
    combine_kernel<<<NTOK, 256, 0, stream>>>(CONTRIB, row_of_pair, out);
}